// Round 8
// baseline (255.471 us; speedup 1.0000x reference)
//
#include <hip/hip_runtime.h>

// ---------- types ----------
typedef unsigned short u16;
using bf16x8 = __attribute__((ext_vector_type(8))) short;
using f32x4  = __attribute__((ext_vector_type(4))) float;

#define GLD16(g, l)                                                            \
  __builtin_amdgcn_global_load_lds(                                            \
      (const __attribute__((address_space(1))) void*)(g),                      \
      (__attribute__((address_space(3))) void*)(l), 16, 0, 0)

__device__ __forceinline__ u16 f2b(float x) {
  union { float f; unsigned u; } v; v.f = x;
  unsigned r = v.u + 0x7FFF + ((v.u >> 16) & 1);
  return (u16)(r >> 16);
}
__device__ __forceinline__ float b2f(u16 x) {
  union { unsigned u; float f; } v; v.u = (unsigned)x << 16; return v.f;
}

// ---------- prep kernels ----------
__global__ void cast_bf16_kernel(const float* __restrict__ in,
                                 u16* __restrict__ out, int n4) {
  int i = blockIdx.x * blockDim.x + threadIdx.x;
  int stride = gridDim.x * blockDim.x;
  for (; i < n4; i += stride) {
    float4 v = ((const float4*)in)[i];
    ushort4 o;
    o.x = f2b(v.x); o.y = f2b(v.y); o.z = f2b(v.z); o.w = f2b(v.w);
    ((ushort4*)out)[i] = o;
  }
}

// All four weight transposes in one launch. f32 [2048][N] -> bf16 [N][2048].
// bx<64: Wq -> Wqkv_bt rows 0..2047;  bx<80: Wk -> rows 2048..2559;
// bx<96: Wv -> rows 2560..3071;       else:  Wo -> Wo_bt rows 0..2047.
__global__ void transpose_all_w_kernel(const float* __restrict__ Wq,
                                       const float* __restrict__ Wk,
                                       const float* __restrict__ Wv,
                                       const float* __restrict__ Wo,
                                       u16* __restrict__ Wqkv_bt,
                                       u16* __restrict__ Wo_bt) {
  __shared__ float tile[32][33];
  const int bx = blockIdx.x, k0 = blockIdx.y * 32;
  const int tx = threadIdx.x, ty = threadIdx.y;  // (32,8)
  const float* src; int srcN, n0s; u16* dst; int dstRow0;
  if (bx < 64)      { src = Wq; srcN = 2048; n0s = bx * 32;        dst = Wqkv_bt; dstRow0 = bx * 32; }
  else if (bx < 80) { src = Wk; srcN = 512;  n0s = (bx - 64) * 32; dst = Wqkv_bt; dstRow0 = 2048 + (bx - 64) * 32; }
  else if (bx < 96) { src = Wv; srcN = 512;  n0s = (bx - 80) * 32; dst = Wqkv_bt; dstRow0 = 2560 + (bx - 80) * 32; }
  else              { src = Wo; srcN = 2048; n0s = (bx - 96) * 32; dst = Wo_bt;   dstRow0 = (bx - 96) * 32; }
#pragma unroll
  for (int r = 0; r < 4; r++)
    tile[ty + r * 8][tx] = src[(size_t)(k0 + ty + r * 8) * srcN + n0s + tx];
  __syncthreads();
#pragma unroll
  for (int r = 0; r < 4; r++)
    dst[(size_t)(dstRow0 + ty + r * 8) * 2048 + k0 + tx] = f2b(tile[tx][ty + r * 8]);
}

// V bf16 [4][2048][128] -> Vt bf16 [4][128][2048]
__global__ void transpose_v_kernel(const u16* __restrict__ src,
                                   u16* __restrict__ dst) {
  __shared__ u16 tile[32][33];
  int h = blockIdx.z;
  int t0 = blockIdx.x * 32, d0 = blockIdx.y * 32;
  const u16* s = src + (size_t)h * 2048 * 128;
  u16* d = dst + (size_t)h * 128 * 2048;
  int tx = threadIdx.x, ty = threadIdx.y;  // (32,8)
#pragma unroll
  for (int r = 0; r < 4; r++)
    tile[ty + r * 8][tx] = s[(size_t)(t0 + ty + r * 8) * 128 + d0 + tx];
  __syncthreads();
#pragma unroll
  for (int r = 0; r < 4; r++)
    d[(size_t)(d0 + ty + r * 8) * 2048 + t0 + tx] = tile[tx][ty + r * 8];
}

// ---------- GEMM: C[M][N] f32 = A[M][K] bf16 * Bt[N][K] bf16 ----------
// 4-buffer LDS pipeline, prefetch distance 2, counted vmcnt (never 0 in loop).
__global__ __launch_bounds__(256, 2)
void gemm_bt_128(const u16* __restrict__ A, const u16* __restrict__ Bt,
                 float* __restrict__ C, int M, int N, int K) {
  __shared__ u16 As[4][128 * 32];
  __shared__ u16 Bs[4][128 * 32];
  const int tid = threadIdx.x;
  const int lane = tid & 63;
  const int w = tid >> 6;
  const int wr = w >> 1, wc = w & 1;
  const int m0 = blockIdx.y * 128, n0 = blockIdx.x * 128;

  f32x4 acc[4][4] = {};

  const int srow = tid >> 2, skg = tid & 3;
  const u16* Ag0 = A + (size_t)(m0 + srow) * K + skg * 8;
  const u16* Ag1 = A + (size_t)(m0 + 64 + srow) * K + skg * 8;
  const u16* Bg0 = Bt + (size_t)(n0 + srow) * K + skg * 8;
  const u16* Bg1 = Bt + (size_t)(n0 + 64 + srow) * K + skg * 8;

  const int l0 = tid * 8, l1 = (256 + tid) * 8;
  u16 *pa0 = As[0], *pa1 = As[1], *pa2 = As[2], *pa3 = As[3];
  u16 *pb0 = Bs[0], *pb1 = Bs[1], *pb2 = Bs[2], *pb3 = Bs[3];

#define GSTAGE(k0v, pa, pb)                                                    \
  {                                                                            \
    GLD16(Ag0 + (k0v), (pa) + l0);                                             \
    GLD16(Ag1 + (k0v), (pa) + l1);                                             \
    GLD16(Bg0 + (k0v), (pb) + l0);                                             \
    GLD16(Bg1 + (k0v), (pb) + l1);                                             \
  }

  // prologue: stage k-steps 0 and 1
  GSTAGE(0, pa0, pb0);
  GSTAGE(32, pa1, pb1);

  const int frow = lane & 15, fk = (lane >> 4) * 8;
  const int nk = K >> 5;

  for (int i = 0; i < nk; ++i) {
    if (i + 2 < nk) {
      GSTAGE((i + 2) * 32, pa2, pb2);
      asm volatile("s_waitcnt vmcnt(8)" ::: "memory");  // my stage(i) done
    } else if (i + 1 < nk) {
      asm volatile("s_waitcnt vmcnt(4)" ::: "memory");
    } else {
      asm volatile("s_waitcnt vmcnt(0)" ::: "memory");
    }
    __builtin_amdgcn_s_barrier();        // all waves' stage(i) done
    __builtin_amdgcn_sched_barrier(0);   // keep ds_reads below the barrier
    bf16x8 av[4], bv[4];
#pragma unroll
    for (int m = 0; m < 4; m++)
      av[m] = *(const bf16x8*)(pa0 + (wr * 64 + m * 16 + frow) * 32 + fk);
#pragma unroll
    for (int n = 0; n < 4; n++)
      bv[n] = *(const bf16x8*)(pb0 + (wc * 64 + n * 16 + frow) * 32 + fk);
#pragma unroll
    for (int m = 0; m < 4; m++)
#pragma unroll
      for (int n = 0; n < 4; n++)
        acc[m][n] =
            __builtin_amdgcn_mfma_f32_16x16x32_bf16(av[m], bv[n], acc[m][n], 0, 0, 0);
    u16* t;
    t = pa0; pa0 = pa1; pa1 = pa2; pa2 = pa3; pa3 = t;
    t = pb0; pb0 = pb1; pb1 = pb2; pb2 = pb3; pb3 = t;
  }
#undef GSTAGE

  const int crow = (lane >> 4) * 4, ccol = lane & 15;
#pragma unroll
  for (int m = 0; m < 4; m++)
#pragma unroll
    for (int n = 0; n < 4; n++)
#pragma unroll
      for (int r = 0; r < 4; r++)
        C[(size_t)(m0 + wr * 64 + m * 16 + crow + r) * N +
          (n0 + wc * 64 + n * 16 + ccol)] = acc[m][n][r];
}

// ---------- RoPE + split/reshape (shared sin/cos table per t) ----------
__global__ void rope_kernel(const float* __restrict__ QKV,
                            const int* __restrict__ pos, u16* __restrict__ Qb,
                            u16* __restrict__ Kb, u16* __restrict__ Vb) {
  __shared__ float sc_[64], cc_[64];
  const int t = blockIdx.x, tid = threadIdx.x;
  const float p = (float)pos[t];
  const float* row = QKV + (size_t)t * 3072;
  const float qscale = 0.08838834764831845f;  // 1/sqrt(128)
  const float c0 = -0.015625f * 13.287712379549449f;  // -(1/64)*log2(10000)
  if (tid < 64) {
    float ang = p * exp2f((float)tid * c0);
    sc_[tid] = sinf(ang);
    cc_[tid] = cosf(ang);
  }
  __syncthreads();
#pragma unroll
  for (int i = 0; i < 4; i++) {
    int idx = tid + i * 256;
    int head = idx >> 6, d = idx & 63;
    float s = sc_[d], c = cc_[d];
    float a0 = row[head * 128 + d], a1 = row[head * 128 + d + 64];
    Qb[((size_t)head * 2048 + t) * 128 + d] = f2b((a0 * c - a1 * s) * qscale);
    Qb[((size_t)head * 2048 + t) * 128 + d + 64] = f2b((a1 * c + a0 * s) * qscale);
  }
  {
    int head = tid >> 6, d = tid & 63;
    float s = sc_[d], c = cc_[d];
    float a0 = row[2048 + head * 128 + d], a1 = row[2048 + head * 128 + d + 64];
    Kb[((size_t)head * 2048 + t) * 128 + d] = f2b(a0 * c - a1 * s);
    Kb[((size_t)head * 2048 + t) * 128 + d + 64] = f2b(a1 * c + a0 * s);
  }
#pragma unroll
  for (int i = 0; i < 2; i++) {
    int e = tid + i * 256;
    int kh = e >> 7, d = e & 127;
    Vb[((size_t)kh * 2048 + t) * 128 + d] = f2b(row[2560 + e]);
  }
}

// ---------- Flash attention v4 (causal, GQA, load-balanced, j-split) ----------
// grid (16 pairs, 16 heads, 2 j-parities) = 512 blocks (2 blocks/CU).
// Block (bx,h,z): q-tiles bx then 31-bx, processing only j-tiles of parity z.
// Writes normalized partial O (bf16) + (m,l) (f32); combine kernel merges.
__global__ __launch_bounds__(256, 2)
void attn_kernel(const u16* __restrict__ Qb, const u16* __restrict__ Kb,
                 const u16* __restrict__ Vtb, u16* __restrict__ Op,
                 float* __restrict__ ml) {
  __shared__ u16 Ks[2][64 * 128];   // [j 0..63][d 0..127], 16B-chunk XOR swizzle
  __shared__ u16 Vs[2][128 * 64];   // [d 0..127][j 0..63], 16B-chunk XOR swizzle
  __shared__ u16 Ps[4][16 * 64];    // per-wave P tile, swizzled
  const int tid = threadIdx.x, lane = tid & 63, w = tid >> 6;
  const int h = blockIdx.y, g = h >> 2;
  const int z = blockIdx.z;
  const int frow = lane & 15, fgrp = lane >> 4;
  const int t0 = blockIdx.x;        // first q-tile (0..15)
  const int t1 = 31 - t0;           // second q-tile (16..31)
  const int c0 = (t0 >= z) ? ((t0 - z) >> 1) + 1 : 0;  // my tiles in pass 0
  const int c1 = ((t1 - z) >> 1) + 1;                  // my tiles in pass 1
  const int nit = c0 + c1;          // 17 (z=0) or 16 (z=1)

  const u16* Kg = Kb + (size_t)g * 2048 * 128;
  const u16* Vg = Vtb + (size_t)g * 128 * 2048;

#define STAGE(j0v, B)                                                          \
  {                                                                            \
    _Pragma("unroll")                                                          \
    for (int i = 0; i < 4; i++) {                                              \
      int p = tid + i * 256;                                                   \
      int kr = p >> 4, kc = (p & 15) ^ (kr & 7);                               \
      GLD16(Kg + (size_t)((j0v) + kr) * 128 + kc * 8, &Ks[B][p * 8]);          \
      int vr = p >> 3, vc = (p & 7) ^ (vr & 7);                                \
      GLD16(Vg + (size_t)vr * 2048 + (j0v) + vc * 8, &Vs[B][p * 8]);           \
    }                                                                          \
  }

  // flush: write normalized partial O + (m,l) for current pass rows
#define FLUSH()                                                                \
  {                                                                            \
    _Pragma("unroll")                                                          \
    for (int r = 0; r < 4; r++) {                                              \
      float inv = lrow[r] > 0.f ? 1.0f / lrow[r] : 0.f;                        \
      int t = qw + fgrp * 4 + r;                                               \
      _Pragma("unroll")                                                        \
      for (int db = 0; db < 8; db++)                                           \
        Op[(size_t)z * 4194304 + (size_t)t * 2048 + h * 128 + db * 16 + frow] =\
            f2b(o[db][r] * inv);                                               \
      if (frow == 0) {                                                         \
        int mi = (((z * 16 + h) * 2048) + t) * 2;                              \
        ml[mi] = mrow[r]; ml[mi + 1] = lrow[r];                                \
      }                                                                        \
    }                                                                          \
  }

  int qw = t0 * 64 + w * 16;
  bf16x8 qf[4];
  {
    const u16* Qrow = Qb + ((size_t)h * 2048 + (qw + frow)) * 128 + fgrp * 8;
#pragma unroll
    for (int kf = 0; kf < 4; kf++) qf[kf] = *(const bf16x8*)(Qrow + kf * 32);
  }

  f32x4 o[8] = {};
  float mrow[4], lrow[4];
#pragma unroll
  for (int r = 0; r < 4; r++) { mrow[r] = -1e30f; lrow[r] = 0.f; }

  // first tile is j=z in whichever pass comes first
  STAGE(z * 64, 0);
  __syncthreads();

  for (int it = 0; it < nit; ++it) {
    const int buf = it & 1;
    // prefetch next tile of my parity (crosses the pass boundary seamlessly)
    if (it + 1 < nit) {
      const int itn = it + 1;
      const int jn = (itn < c0) ? z + 2 * itn : z + 2 * (itn - c0);
      STAGE(jn * 64, buf ^ 1);
    }
    // pass boundary: flush pass-0 partial, reset state, load pass-1 Q
    if (it == c0) {
      FLUSH();
#pragma unroll
      for (int db = 0; db < 8; db++)
#pragma unroll
        for (int r = 0; r < 4; r++) o[db][r] = 0.f;
#pragma unroll
      for (int r = 0; r < 4; r++) { mrow[r] = -1e30f; lrow[r] = 0.f; }
      qw = t1 * 64 + w * 16;
      const u16* Qrow = Qb + ((size_t)h * 2048 + (qw + frow)) * 128 + fgrp * 8;
#pragma unroll
      for (int kf = 0; kf < 4; kf++) qf[kf] = *(const bf16x8*)(Qrow + kf * 32);
    }
    const int pass = (it < c0) ? 0 : 1;
    const int j = (pass == 0) ? z + 2 * it : z + 2 * (it - c0);
    const bool diag = (pass == 0) ? (j == t0) : (j == t1);

    // S = Q K^T  (16 rows x 64 cols)
    f32x4 sc[4] = {};
#pragma unroll
    for (int c = 0; c < 4; c++)
#pragma unroll
      for (int kf = 0; kf < 4; kf++) {
        int row = c * 16 + frow;
        bf16x8 kv = *(const bf16x8*)(
            &Ks[buf][row * 128 + ((kf * 4 + fgrp) ^ (row & 7)) * 8]);
        sc[c] = __builtin_amdgcn_mfma_f32_16x16x32_bf16(qf[kf], kv, sc[c], 0, 0, 0);
      }
    // causal mask — diagonal tile only (j-tile base == pass q-tile base)
    if (diag) {
#pragma unroll
      for (int c = 0; c < 4; c++) {
        int jj = c * 16 + frow;  // j relative to tile == q relative to tile
#pragma unroll
        for (int r = 0; r < 4; r++)
          if (jj > (w * 16 + fgrp * 4 + r)) sc[c][r] = -1e30f;
      }
    }
    // online softmax with defer-max (THR=8)
    float pm[4];
#pragma unroll
    for (int r = 0; r < 4; r++)
      pm[r] = fmaxf(fmaxf(sc[0][r], sc[1][r]), fmaxf(sc[2][r], sc[3][r]));
#pragma unroll
    for (int off = 1; off < 16; off <<= 1)
#pragma unroll
      for (int r = 0; r < 4; r++) pm[r] = fmaxf(pm[r], __shfl_xor(pm[r], off, 64));
    bool nd = false;
#pragma unroll
    for (int r = 0; r < 4; r++) nd = nd || (pm[r] > mrow[r] + 8.f);
    if (__any(nd)) {
#pragma unroll
      for (int r = 0; r < 4; r++) {
        float mn = fmaxf(mrow[r], pm[r]);
        float alpha = __expf(mrow[r] - mn);
        mrow[r] = mn;
        lrow[r] *= alpha;
#pragma unroll
        for (int db = 0; db < 8; db++) o[db][r] *= alpha;
      }
    }
    float rs[4];
#pragma unroll
    for (int r = 0; r < 4; r++) {
      float s = 0.f;
#pragma unroll
      for (int c = 0; c < 4; c++) { sc[c][r] = __expf(sc[c][r] - mrow[r]); s += sc[c][r]; }
      rs[r] = s;
    }
#pragma unroll
    for (int off = 1; off < 16; off <<= 1)
#pragma unroll
      for (int r = 0; r < 4; r++) rs[r] += __shfl_xor(rs[r], off, 64);
#pragma unroll
    for (int r = 0; r < 4; r++) lrow[r] += rs[r];
    // P (D-layout) -> swizzled per-wave LDS -> A-layout fragments
    u16* Pw = Ps[w];
#pragma unroll
    for (int c = 0; c < 4; c++)
#pragma unroll
      for (int r = 0; r < 4; r++) {
        int row = fgrp * 4 + r, col = c * 16 + frow;
        Pw[row * 64 + (((col >> 3) ^ row) & 7) * 8 + (col & 7)] = f2b(sc[c][r]);
      }
    asm volatile("s_waitcnt lgkmcnt(0)" ::: "memory");
    bf16x8 pf[2];
#pragma unroll
    for (int ks = 0; ks < 2; ks++)
      pf[ks] = *(const bf16x8*)(
          &Pw[frow * 64 + ((ks * 4 + fgrp) ^ (frow & 7)) * 8]);
#pragma unroll
    for (int db = 0; db < 8; db++)
#pragma unroll
      for (int ks = 0; ks < 2; ks++) {
        int row = db * 16 + frow;
        bf16x8 vf = *(const bf16x8*)(
            &Vs[buf][row * 64 + ((ks * 4 + fgrp) ^ (row & 7)) * 8]);
        o[db] = __builtin_amdgcn_mfma_f32_16x16x32_bf16(pf[ks], vf, o[db], 0, 0, 0);
      }
    __syncthreads();
  }
  // epilogue: pass-1 partial
  FLUSH();
#undef STAGE
#undef FLUSH
}

// ---------- combine the two j-parity partials -> Y bf16 [2048][2048] ----------
__global__ void attn_combine_kernel(const u16* __restrict__ Op,
                                    const float* __restrict__ ml,
                                    u16* __restrict__ Y) {
  int u = blockIdx.x * blockDim.x + threadIdx.x;  // 0..32767 = t*16 + h
  int t = u >> 4, h = u & 15;
  int i0 = ((0 * 16 + h) * 2048 + t) * 2;
  int i1 = ((1 * 16 + h) * 2048 + t) * 2;
  float m0 = ml[i0], l0 = ml[i0 + 1];
  float m1 = ml[i1], l1 = ml[i1 + 1];
  float m = fmaxf(m0, m1);
  float w0 = __expf(m0 - m) * l0, w1 = __expf(m1 - m) * l1;
  float inv = 1.0f / (w0 + w1);  // every row has >=1 unmasked col -> sum > 0
  w0 *= inv; w1 *= inv;
  size_t base = (size_t)t * 2048 + h * 128;
#pragma unroll
  for (int i = 0; i < 16; i++) {
    bf16x8 a = *(const bf16x8*)(Op + base + i * 8);
    bf16x8 b = *(const bf16x8*)(Op + 4194304 + base + i * 8);
    bf16x8 out;
#pragma unroll
    for (int jj = 0; jj < 8; jj++)
      out[jj] = (short)f2b(w0 * b2f((u16)a[jj]) + w1 * b2f((u16)b[jj]));
    *(bf16x8*)(Y + base + i * 8) = out;
  }
}

// ---------- launch ----------
extern "C" void kernel_launch(void* const* d_in, const int* in_sizes, int n_in,
                              void* d_out, int out_size, void* d_ws,
                              size_t ws_size, hipStream_t stream) {
  const float* x  = (const float*)d_in[0];
  const float* Wq = (const float*)d_in[1];
  const float* Wk = (const float*)d_in[2];
  const float* Wv = (const float*)d_in[3];
  const float* Wo = (const float*)d_in[4];
  const int* pos  = (const int*)d_in[5];
  float* out = (float*)d_out;
  char* ws = (char*)d_ws;

  u16* xb      = (u16*)(ws + 0);          // 8 MB   (dead after gemm1)
  u16* Wqkv_bt = (u16*)(ws + 8388608);    // 12.6 MB (dead after gemm1)
  u16* Wo_bt   = (u16*)(ws + 20971520);   // 8 MB
  float* QKV   = (float*)(ws + 29360128); // 25.2 MB (dead after rope)
  u16* Yb      = (u16*)(ws + 29360128);   // overlaps QKV
  u16* Qb      = (u16*)(ws + 54525952);   // 8 MB
  u16* Kb      = (u16*)(ws + 62914560);   // 2 MB
  u16* Vb      = (u16*)(ws + 65011712);   // 2 MB
  u16* Vtb     = (u16*)(ws + 67108864);   // 2 MB  (end 69206016)
  u16* Op      = (u16*)(ws + 0);          // 16 MB partial O, reuses xb/Wqkv
  float* ml    = (float*)(ws + 16777216); // 0.5 MB (m,l) pairs, < Wo_bt start

  cast_bf16_kernel<<<1024, 256, 0, stream>>>(x, xb, 2048 * 2048 / 4);
  transpose_all_w_kernel<<<dim3(160, 64), dim3(32, 8), 0, stream>>>(
      Wq, Wk, Wv, Wo, Wqkv_bt, Wo_bt);

  gemm_bt_128<<<dim3(3072 / 128, 2048 / 128), 256, 0, stream>>>(xb, Wqkv_bt, QKV, 2048, 3072, 2048);

  rope_kernel<<<2048, 256, 0, stream>>>(QKV, pos, Qb, Kb, Vb);
  transpose_v_kernel<<<dim3(64, 4, 4), dim3(32, 8), 0, stream>>>(Vb, Vtb);

  attn_kernel<<<dim3(16, 16, 2), 256, 0, stream>>>(Qb, Kb, Vtb, Op, ml);
  attn_combine_kernel<<<128, 256, 0, stream>>>(Op, ml, Yb);

  gemm_bt_128<<<dim3(2048 / 128, 2048 / 128), 256, 0, stream>>>(Yb, Wo_bt, out, 2048, 2048, 2048);
}

// Round 9
// 242.154 us; speedup vs baseline: 1.0550x; 1.0550x over previous
//
#include <hip/hip_runtime.h>

// ---------- types ----------
typedef unsigned short u16;
using bf16x8 = __attribute__((ext_vector_type(8))) short;
using f32x4  = __attribute__((ext_vector_type(4))) float;

#define GLD16(g, l)                                                            \
  __builtin_amdgcn_global_load_lds(                                            \
      (const __attribute__((address_space(1))) void*)(g),                      \
      (__attribute__((address_space(3))) void*)(l), 16, 0, 0)

__device__ __forceinline__ u16 f2b(float x) {
  union { float f; unsigned u; } v; v.f = x;
  unsigned r = v.u + 0x7FFF + ((v.u >> 16) & 1);
  return (u16)(r >> 16);
}
__device__ __forceinline__ float b2f(u16 x) {
  union { unsigned u; float f; } v; v.u = (unsigned)x << 16; return v.f;
}

// ---------- cast + rope-table kernel ----------
// out = bf16(x); tbl[t*64+d] = (cos, sin) of pos[t] * base^(-d/64)
__global__ void cast_bf16_kernel(const float* __restrict__ in,
                                 u16* __restrict__ out, int n4,
                                 const int* __restrict__ pos,
                                 float2* __restrict__ tbl) {
  int gid = blockIdx.x * blockDim.x + threadIdx.x;
  int stride = gridDim.x * blockDim.x;
  const float c0 = -0.015625f * 13.287712379549449f;  // -(1/64)*log2(10000)
  for (int j = gid; j < 2048 * 64; j += stride) {
    int t = j >> 6, d = j & 63;
    float ang = (float)pos[t] * exp2f((float)d * c0);
    tbl[j] = make_float2(cosf(ang), sinf(ang));
  }
  for (int i = gid; i < n4; i += stride) {
    float4 v = ((const float4*)in)[i];
    ushort4 o;
    o.x = f2b(v.x); o.y = f2b(v.y); o.z = f2b(v.z); o.w = f2b(v.w);
    ((ushort4*)out)[i] = o;
  }
}

// All four weight transposes in one launch. f32 [2048][N] -> bf16 [N][2048].
__global__ void transpose_all_w_kernel(const float* __restrict__ Wq,
                                       const float* __restrict__ Wk,
                                       const float* __restrict__ Wv,
                                       const float* __restrict__ Wo,
                                       u16* __restrict__ Wqkv_bt,
                                       u16* __restrict__ Wo_bt) {
  __shared__ float tile[32][33];
  const int bx = blockIdx.x, k0 = blockIdx.y * 32;
  const int tx = threadIdx.x, ty = threadIdx.y;  // (32,8)
  const float* src; int srcN, n0s; u16* dst; int dstRow0;
  if (bx < 64)      { src = Wq; srcN = 2048; n0s = bx * 32;        dst = Wqkv_bt; dstRow0 = bx * 32; }
  else if (bx < 80) { src = Wk; srcN = 512;  n0s = (bx - 64) * 32; dst = Wqkv_bt; dstRow0 = 2048 + (bx - 64) * 32; }
  else if (bx < 96) { src = Wv; srcN = 512;  n0s = (bx - 80) * 32; dst = Wqkv_bt; dstRow0 = 2560 + (bx - 80) * 32; }
  else              { src = Wo; srcN = 2048; n0s = (bx - 96) * 32; dst = Wo_bt;   dstRow0 = (bx - 96) * 32; }
#pragma unroll
  for (int r = 0; r < 4; r++)
    tile[ty + r * 8][tx] = src[(size_t)(k0 + ty + r * 8) * srcN + n0s + tx];
  __syncthreads();
#pragma unroll
  for (int r = 0; r < 4; r++)
    dst[(size_t)(dstRow0 + ty + r * 8) * 2048 + k0 + tx] = f2b(tile[tx][ty + r * 8]);
}

// V bf16 [4][2048][128] -> Vt bf16 [4][128][2048]
__global__ void transpose_v_kernel(const u16* __restrict__ src,
                                   u16* __restrict__ dst) {
  __shared__ u16 tile[32][33];
  int h = blockIdx.z;
  int t0 = blockIdx.x * 32, d0 = blockIdx.y * 32;
  const u16* s = src + (size_t)h * 2048 * 128;
  u16* d = dst + (size_t)h * 128 * 2048;
  int tx = threadIdx.x, ty = threadIdx.y;  // (32,8)
#pragma unroll
  for (int r = 0; r < 4; r++)
    tile[ty + r * 8][tx] = s[(size_t)(t0 + ty + r * 8) * 128 + d0 + tx];
  __syncthreads();
#pragma unroll
  for (int r = 0; r < 4; r++)
    d[(size_t)(d0 + ty + r * 8) * 2048 + t0 + tx] = tile[tx][ty + r * 8];
}

// ---------- GEMM1 + fused RoPE epilogue ----------
// A[2048][2048] bf16 x Wqkv_bt[3072][2048] bf16. Tile 128x128 = one head slice.
// Q tiles (n0<2048): rope + 1/sqrt(128) -> Qb [16][2048][128]
// K tiles (2048<=n0<2560): rope -> Kb [4][2048][128]
// V tiles (n0>=2560): cast -> Vb [4][2048][128]
// Rope pairing (d, d^64) crosses the two wc-halves: exchange via staging LDS.
__global__ __launch_bounds__(256, 2)
void gemm_qkv_rope(const u16* __restrict__ A, const u16* __restrict__ Bt,
                   const float2* __restrict__ tbl, u16* __restrict__ Qb,
                   u16* __restrict__ Kb, u16* __restrict__ Vb) {
  __shared__ u16 lds_[8][128 * 32];  // [0..3]=A bufs, [4..7]=B bufs (64 KB)
  const int K = 2048;
  const int tid = threadIdx.x;
  const int lane = tid & 63;
  const int w = tid >> 6;
  const int wr = w >> 1, wc = w & 1;
  const int m0 = blockIdx.y * 128, n0 = blockIdx.x * 128;

  f32x4 acc[4][4] = {};

  const int srow = tid >> 2, skg = tid & 3;
  const u16* Ag0 = A + (size_t)(m0 + srow) * K + skg * 8;
  const u16* Ag1 = A + (size_t)(m0 + 64 + srow) * K + skg * 8;
  const u16* Bg0 = Bt + (size_t)(n0 + srow) * K + skg * 8;
  const u16* Bg1 = Bt + (size_t)(n0 + 64 + srow) * K + skg * 8;

  const int l0 = tid * 8, l1 = (256 + tid) * 8;
  u16 *pa0 = lds_[0], *pa1 = lds_[1], *pa2 = lds_[2], *pa3 = lds_[3];
  u16 *pb0 = lds_[4], *pb1 = lds_[5], *pb2 = lds_[6], *pb3 = lds_[7];

#define GSTAGE(k0v, pa, pb)                                                    \
  {                                                                            \
    GLD16(Ag0 + (k0v), (pa) + l0);                                             \
    GLD16(Ag1 + (k0v), (pa) + l1);                                             \
    GLD16(Bg0 + (k0v), (pb) + l0);                                             \
    GLD16(Bg1 + (k0v), (pb) + l1);                                             \
  }

  GSTAGE(0, pa0, pb0);
  GSTAGE(32, pa1, pb1);

  const int frow = lane & 15, fk = (lane >> 4) * 8;
  const int nk = K >> 5;

  for (int i = 0; i < nk; ++i) {
    if (i + 2 < nk) {
      GSTAGE((i + 2) * 32, pa2, pb2);
      asm volatile("s_waitcnt vmcnt(8)" ::: "memory");
    } else if (i + 1 < nk) {
      asm volatile("s_waitcnt vmcnt(4)" ::: "memory");
    } else {
      asm volatile("s_waitcnt vmcnt(0)" ::: "memory");
    }
    __builtin_amdgcn_s_barrier();
    __builtin_amdgcn_sched_barrier(0);
    bf16x8 av[4], bv[4];
#pragma unroll
    for (int m = 0; m < 4; m++)
      av[m] = *(const bf16x8*)(pa0 + (wr * 64 + m * 16 + frow) * 32 + fk);
#pragma unroll
    for (int n = 0; n < 4; n++)
      bv[n] = *(const bf16x8*)(pb0 + (wc * 64 + n * 16 + frow) * 32 + fk);
#pragma unroll
    for (int m = 0; m < 4; m++)
#pragma unroll
      for (int n = 0; n < 4; n++)
        acc[m][n] =
            __builtin_amdgcn_mfma_f32_16x16x32_bf16(av[m], bv[n], acc[m][n], 0, 0, 0);
    u16* t;
    t = pa0; pa0 = pa1; pa1 = pa2; pa2 = pa3; pa3 = t;
    t = pb0; pb0 = pb1; pb1 = pb2; pb2 = pb3; pb3 = t;
  }
#undef GSTAGE

  const int crow = (lane >> 4) * 4, ccol = lane & 15;
  if (n0 < 2560) {
    // Q or K: exchange the d^64 partner via LDS scratch (staging bufs are dead)
    __syncthreads();  // full drain: all waves done with staging LDS
    float* S = (float*)lds_;  // 128x128 f32 = 64 KB
#pragma unroll
    for (int m = 0; m < 4; m++)
#pragma unroll
      for (int n = 0; n < 4; n++)
#pragma unroll
        for (int r = 0; r < 4; r++)
          S[(wr * 64 + m * 16 + crow + r) * 128 + wc * 64 + n * 16 + ccol] =
              acc[m][n][r];
    __syncthreads();
    const bool isQ = (n0 < 2048);
    u16* dst = isQ ? Qb + (size_t)(n0 >> 7) * 2048 * 128
                   : Kb + (size_t)((n0 - 2048) >> 7) * 2048 * 128;
    const float sgn = (wc == 0) ? -1.f : 1.f;  // col<64: -sin ; col>=64: +sin
    const float qs = isQ ? 0.08838834764831845f : 1.0f;  // 1/sqrt(128)
#pragma unroll
    for (int m = 0; m < 4; m++)
#pragma unroll
      for (int n = 0; n < 4; n++)
#pragma unroll
        for (int r = 0; r < 4; r++) {
          int row = wr * 64 + m * 16 + crow + r;
          int col = wc * 64 + n * 16 + ccol;
          int t = m0 + row, d = col & 63;
          float2 cs = tbl[t * 64 + d];
          float val = acc[m][n][r] * cs.x + sgn * S[row * 128 + (col ^ 64)] * cs.y;
          dst[(size_t)t * 128 + col] = f2b(val * qs);
        }
  } else {
    // V: plain bf16 cast
    u16* dst = Vb + (size_t)((n0 - 2560) >> 7) * 2048 * 128;
#pragma unroll
    for (int m = 0; m < 4; m++)
#pragma unroll
      for (int n = 0; n < 4; n++)
#pragma unroll
        for (int r = 0; r < 4; r++) {
          int row = wr * 64 + m * 16 + crow + r;
          int col = wc * 64 + n * 16 + ccol;
          dst[(size_t)(m0 + row) * 128 + col] = f2b(acc[m][n][r]);
        }
  }
}

// ---------- GEMM: C[M][N] f32 = A[M][K] bf16 * Bt[N][K] bf16 ----------
// 4-buffer LDS pipeline, prefetch distance 2, counted vmcnt (never 0 in loop).
__global__ __launch_bounds__(256, 2)
void gemm_bt_128(const u16* __restrict__ A, const u16* __restrict__ Bt,
                 float* __restrict__ C, int M, int N, int K) {
  __shared__ u16 As[4][128 * 32];
  __shared__ u16 Bs[4][128 * 32];
  const int tid = threadIdx.x;
  const int lane = tid & 63;
  const int w = tid >> 6;
  const int wr = w >> 1, wc = w & 1;
  const int m0 = blockIdx.y * 128, n0 = blockIdx.x * 128;

  f32x4 acc[4][4] = {};

  const int srow = tid >> 2, skg = tid & 3;
  const u16* Ag0 = A + (size_t)(m0 + srow) * K + skg * 8;
  const u16* Ag1 = A + (size_t)(m0 + 64 + srow) * K + skg * 8;
  const u16* Bg0 = Bt + (size_t)(n0 + srow) * K + skg * 8;
  const u16* Bg1 = Bt + (size_t)(n0 + 64 + srow) * K + skg * 8;

  const int l0 = tid * 8, l1 = (256 + tid) * 8;
  u16 *pa0 = As[0], *pa1 = As[1], *pa2 = As[2], *pa3 = As[3];
  u16 *pb0 = Bs[0], *pb1 = Bs[1], *pb2 = Bs[2], *pb3 = Bs[3];

#define GSTAGE(k0v, pa, pb)                                                    \
  {                                                                            \
    GLD16(Ag0 + (k0v), (pa) + l0);                                             \
    GLD16(Ag1 + (k0v), (pa) + l1);                                             \
    GLD16(Bg0 + (k0v), (pb) + l0);                                             \
    GLD16(Bg1 + (k0v), (pb) + l1);                                             \
  }

  GSTAGE(0, pa0, pb0);
  GSTAGE(32, pa1, pb1);

  const int frow = lane & 15, fk = (lane >> 4) * 8;
  const int nk = K >> 5;

  for (int i = 0; i < nk; ++i) {
    if (i + 2 < nk) {
      GSTAGE((i + 2) * 32, pa2, pb2);
      asm volatile("s_waitcnt vmcnt(8)" ::: "memory");
    } else if (i + 1 < nk) {
      asm volatile("s_waitcnt vmcnt(4)" ::: "memory");
    } else {
      asm volatile("s_waitcnt vmcnt(0)" ::: "memory");
    }
    __builtin_amdgcn_s_barrier();
    __builtin_amdgcn_sched_barrier(0);
    bf16x8 av[4], bv[4];
#pragma unroll
    for (int m = 0; m < 4; m++)
      av[m] = *(const bf16x8*)(pa0 + (wr * 64 + m * 16 + frow) * 32 + fk);
#pragma unroll
    for (int n = 0; n < 4; n++)
      bv[n] = *(const bf16x8*)(pb0 + (wc * 64 + n * 16 + frow) * 32 + fk);
#pragma unroll
    for (int m = 0; m < 4; m++)
#pragma unroll
      for (int n = 0; n < 4; n++)
        acc[m][n] =
            __builtin_amdgcn_mfma_f32_16x16x32_bf16(av[m], bv[n], acc[m][n], 0, 0, 0);
    u16* t;
    t = pa0; pa0 = pa1; pa1 = pa2; pa2 = pa3; pa3 = t;
    t = pb0; pb0 = pb1; pb1 = pb2; pb2 = pb3; pb3 = t;
  }
#undef GSTAGE

  const int crow = (lane >> 4) * 4, ccol = lane & 15;
#pragma unroll
  for (int m = 0; m < 4; m++)
#pragma unroll
    for (int n = 0; n < 4; n++)
#pragma unroll
      for (int r = 0; r < 4; r++)
        C[(size_t)(m0 + wr * 64 + m * 16 + crow + r) * N +
          (n0 + wc * 64 + n * 16 + ccol)] = acc[m][n][r];
}

// ---------- Flash attention v4 (causal, GQA, load-balanced, j-split) ----------
__global__ __launch_bounds__(256, 2)
void attn_kernel(const u16* __restrict__ Qb, const u16* __restrict__ Kb,
                 const u16* __restrict__ Vtb, u16* __restrict__ Op,
                 float* __restrict__ ml) {
  __shared__ u16 Ks[2][64 * 128];   // [j 0..63][d 0..127], 16B-chunk XOR swizzle
  __shared__ u16 Vs[2][128 * 64];   // [d 0..127][j 0..63], 16B-chunk XOR swizzle
  __shared__ u16 Ps[4][16 * 64];    // per-wave P tile, swizzled
  const int tid = threadIdx.x, lane = tid & 63, w = tid >> 6;
  const int h = blockIdx.y, g = h >> 2;
  const int z = blockIdx.z;
  const int frow = lane & 15, fgrp = lane >> 4;
  const int t0 = blockIdx.x;        // first q-tile (0..15)
  const int t1 = 31 - t0;           // second q-tile (16..31)
  const int c0 = (t0 >= z) ? ((t0 - z) >> 1) + 1 : 0;  // my tiles in pass 0
  const int c1 = ((t1 - z) >> 1) + 1;                  // my tiles in pass 1
  const int nit = c0 + c1;          // 17 (z=0) or 16 (z=1)

  const u16* Kg = Kb + (size_t)g * 2048 * 128;
  const u16* Vg = Vtb + (size_t)g * 128 * 2048;

#define STAGE(j0v, B)                                                          \
  {                                                                            \
    _Pragma("unroll")                                                          \
    for (int i = 0; i < 4; i++) {                                              \
      int p = tid + i * 256;                                                   \
      int kr = p >> 4, kc = (p & 15) ^ (kr & 7);                               \
      GLD16(Kg + (size_t)((j0v) + kr) * 128 + kc * 8, &Ks[B][p * 8]);          \
      int vr = p >> 3, vc = (p & 7) ^ (vr & 7);                                \
      GLD16(Vg + (size_t)vr * 2048 + (j0v) + vc * 8, &Vs[B][p * 8]);           \
    }                                                                          \
  }

#define FLUSH()                                                                \
  {                                                                            \
    _Pragma("unroll")                                                          \
    for (int r = 0; r < 4; r++) {                                              \
      float inv = lrow[r] > 0.f ? 1.0f / lrow[r] : 0.f;                        \
      int t = qw + fgrp * 4 + r;                                               \
      _Pragma("unroll")                                                        \
      for (int db = 0; db < 8; db++)                                           \
        Op[(size_t)z * 4194304 + (size_t)t * 2048 + h * 128 + db * 16 + frow] =\
            f2b(o[db][r] * inv);                                               \
      if (frow == 0) {                                                         \
        int mi = (((z * 16 + h) * 2048) + t) * 2;                              \
        ml[mi] = mrow[r]; ml[mi + 1] = lrow[r];                                \
      }                                                                        \
    }                                                                          \
  }

  int qw = t0 * 64 + w * 16;
  bf16x8 qf[4];
  {
    const u16* Qrow = Qb + ((size_t)h * 2048 + (qw + frow)) * 128 + fgrp * 8;
#pragma unroll
    for (int kf = 0; kf < 4; kf++) qf[kf] = *(const bf16x8*)(Qrow + kf * 32);
  }

  f32x4 o[8] = {};
  float mrow[4], lrow[4];
#pragma unroll
  for (int r = 0; r < 4; r++) { mrow[r] = -1e30f; lrow[r] = 0.f; }

  STAGE(z * 64, 0);
  __syncthreads();

  for (int it = 0; it < nit; ++it) {
    const int buf = it & 1;
    if (it + 1 < nit) {
      const int itn = it + 1;
      const int jn = (itn < c0) ? z + 2 * itn : z + 2 * (itn - c0);
      STAGE(jn * 64, buf ^ 1);
    }
    if (it == c0) {
      FLUSH();
#pragma unroll
      for (int db = 0; db < 8; db++)
#pragma unroll
        for (int r = 0; r < 4; r++) o[db][r] = 0.f;
#pragma unroll
      for (int r = 0; r < 4; r++) { mrow[r] = -1e30f; lrow[r] = 0.f; }
      qw = t1 * 64 + w * 16;
      const u16* Qrow = Qb + ((size_t)h * 2048 + (qw + frow)) * 128 + fgrp * 8;
#pragma unroll
      for (int kf = 0; kf < 4; kf++) qf[kf] = *(const bf16x8*)(Qrow + kf * 32);
    }
    const int pass = (it < c0) ? 0 : 1;
    const int j = (pass == 0) ? z + 2 * it : z + 2 * (it - c0);
    const bool diag = (pass == 0) ? (j == t0) : (j == t1);

    f32x4 sc[4] = {};
#pragma unroll
    for (int c = 0; c < 4; c++)
#pragma unroll
      for (int kf = 0; kf < 4; kf++) {
        int row = c * 16 + frow;
        bf16x8 kv = *(const bf16x8*)(
            &Ks[buf][row * 128 + ((kf * 4 + fgrp) ^ (row & 7)) * 8]);
        sc[c] = __builtin_amdgcn_mfma_f32_16x16x32_bf16(qf[kf], kv, sc[c], 0, 0, 0);
      }
    if (diag) {
#pragma unroll
      for (int c = 0; c < 4; c++) {
        int jj = c * 16 + frow;
#pragma unroll
        for (int r = 0; r < 4; r++)
          if (jj > (w * 16 + fgrp * 4 + r)) sc[c][r] = -1e30f;
      }
    }
    float pm[4];
#pragma unroll
    for (int r = 0; r < 4; r++)
      pm[r] = fmaxf(fmaxf(sc[0][r], sc[1][r]), fmaxf(sc[2][r], sc[3][r]));
#pragma unroll
    for (int off = 1; off < 16; off <<= 1)
#pragma unroll
      for (int r = 0; r < 4; r++) pm[r] = fmaxf(pm[r], __shfl_xor(pm[r], off, 64));
    bool nd = false;
#pragma unroll
    for (int r = 0; r < 4; r++) nd = nd || (pm[r] > mrow[r] + 8.f);
    if (__any(nd)) {
#pragma unroll
      for (int r = 0; r < 4; r++) {
        float mn = fmaxf(mrow[r], pm[r]);
        float alpha = __expf(mrow[r] - mn);
        mrow[r] = mn;
        lrow[r] *= alpha;
#pragma unroll
        for (int db = 0; db < 8; db++) o[db][r] *= alpha;
      }
    }
    float rs[4];
#pragma unroll
    for (int r = 0; r < 4; r++) {
      float s = 0.f;
#pragma unroll
      for (int c = 0; c < 4; c++) { sc[c][r] = __expf(sc[c][r] - mrow[r]); s += sc[c][r]; }
      rs[r] = s;
    }
#pragma unroll
    for (int off = 1; off < 16; off <<= 1)
#pragma unroll
      for (int r = 0; r < 4; r++) rs[r] += __shfl_xor(rs[r], off, 64);
#pragma unroll
    for (int r = 0; r < 4; r++) lrow[r] += rs[r];
    u16* Pw = Ps[w];
#pragma unroll
    for (int c = 0; c < 4; c++)
#pragma unroll
      for (int r = 0; r < 4; r++) {
        int row = fgrp * 4 + r, col = c * 16 + frow;
        Pw[row * 64 + (((col >> 3) ^ row) & 7) * 8 + (col & 7)] = f2b(sc[c][r]);
      }
    asm volatile("s_waitcnt lgkmcnt(0)" ::: "memory");
    bf16x8 pf[2];
#pragma unroll
    for (int ks = 0; ks < 2; ks++)
      pf[ks] = *(const bf16x8*)(
          &Pw[frow * 64 + ((ks * 4 + fgrp) ^ (frow & 7)) * 8]);
#pragma unroll
    for (int db = 0; db < 8; db++)
#pragma unroll
      for (int ks = 0; ks < 2; ks++) {
        int row = db * 16 + frow;
        bf16x8 vf = *(const bf16x8*)(
            &Vs[buf][row * 64 + ((ks * 4 + fgrp) ^ (row & 7)) * 8]);
        o[db] = __builtin_amdgcn_mfma_f32_16x16x32_bf16(pf[ks], vf, o[db], 0, 0, 0);
      }
    __syncthreads();
  }
  FLUSH();
#undef STAGE
#undef FLUSH
}

// ---------- combine the two j-parity partials -> Y bf16 [2048][2048] ----------
__global__ void attn_combine_kernel(const u16* __restrict__ Op,
                                    const float* __restrict__ ml,
                                    u16* __restrict__ Y) {
  int u = blockIdx.x * blockDim.x + threadIdx.x;  // 0..32767 = t*16 + h
  int t = u >> 4, h = u & 15;
  int i0 = ((0 * 16 + h) * 2048 + t) * 2;
  int i1 = ((1 * 16 + h) * 2048 + t) * 2;
  float m0 = ml[i0], l0 = ml[i0 + 1];
  float m1 = ml[i1], l1 = ml[i1 + 1];
  float m = fmaxf(m0, m1);
  float w0 = __expf(m0 - m) * l0, w1 = __expf(m1 - m) * l1;
  float inv = 1.0f / (w0 + w1);
  w0 *= inv; w1 *= inv;
  size_t base = (size_t)t * 2048 + h * 128;
#pragma unroll
  for (int i = 0; i < 16; i++) {
    bf16x8 a = *(const bf16x8*)(Op + base + i * 8);
    bf16x8 b = *(const bf16x8*)(Op + 4194304 + base + i * 8);
    bf16x8 out;
#pragma unroll
    for (int jj = 0; jj < 8; jj++)
      out[jj] = (short)f2b(w0 * b2f((u16)a[jj]) + w1 * b2f((u16)b[jj]));
    *(bf16x8*)(Y + base + i * 8) = out;
  }
}

// ---------- launch ----------
extern "C" void kernel_launch(void* const* d_in, const int* in_sizes, int n_in,
                              void* d_out, int out_size, void* d_ws,
                              size_t ws_size, hipStream_t stream) {
  const float* x  = (const float*)d_in[0];
  const float* Wq = (const float*)d_in[1];
  const float* Wk = (const float*)d_in[2];
  const float* Wv = (const float*)d_in[3];
  const float* Wo = (const float*)d_in[4];
  const int* pos  = (const int*)d_in[5];
  float* out = (float*)d_out;
  char* ws = (char*)d_ws;

  u16* xb      = (u16*)(ws + 0);          // 8 MB   (dead after gemm1)
  u16* Wqkv_bt = (u16*)(ws + 8388608);    // 12.6 MB (dead after gemm1)
  u16* Wo_bt   = (u16*)(ws + 20971520);   // 8 MB
  float2* tbl  = (float2*)(ws + 29360128);// 1 MB rope table (dead after gemm1)
  u16* Yb      = (u16*)(ws + 31457280);   // 8 MB
  u16* Qb      = (u16*)(ws + 54525952);   // 8 MB
  u16* Kb      = (u16*)(ws + 62914560);   // 2 MB
  u16* Vb      = (u16*)(ws + 65011712);   // 2 MB
  u16* Vtb     = (u16*)(ws + 67108864);   // 2 MB  (end 69206016)
  u16* Op      = (u16*)(ws + 0);          // 16 MB partial O (reuses xb/Wqkv)
  float* ml    = (float*)(ws + 16777216); // 0.5 MB (m,l) pairs

  cast_bf16_kernel<<<1024, 256, 0, stream>>>(x, xb, 2048 * 2048 / 4, pos, tbl);
  transpose_all_w_kernel<<<dim3(160, 64), dim3(32, 8), 0, stream>>>(
      Wq, Wk, Wv, Wo, Wqkv_bt, Wo_bt);

  gemm_qkv_rope<<<dim3(24, 16), 256, 0, stream>>>(xb, Wqkv_bt, tbl, Qb, Kb, Vb);

  transpose_v_kernel<<<dim3(64, 4, 4), dim3(32, 8), 0, stream>>>(Vb, Vtb);

  attn_kernel<<<dim3(16, 16, 2), 256, 0, stream>>>(Qb, Kb, Vtb, Op, ml);
  attn_combine_kernel<<<128, 256, 0, stream>>>(Op, ml, Yb);

  gemm_bt_128<<<dim3(2048 / 128, 2048 / 128), 256, 0, stream>>>(Yb, Wo_bt, out, 2048, 2048, 2048);
}